// Round 2
// baseline (331.737 us; speedup 1.0000x reference)
//
#include <hip/hip_runtime.h>

#define NN 50000
#define EE 800000
#define DD 512
#define HH 8
#define NBLK 196          // ceil(NN/256)
#define NTILE (NN/16)     // 3125, exact
#define EBLK (EE/256)     // 3125, exact

typedef short bf16x8 __attribute__((ext_vector_type(8)));
typedef float f32x4 __attribute__((ext_vector_type(4)));

union U16 { uint4 u; bf16x8 v; unsigned short h[8]; };

__device__ __forceinline__ unsigned short f2bf(float f) {
    union { float f; unsigned int i; } c; c.f = f;
    unsigned int i = c.i;
    i += 0x7fffu + ((i >> 16) & 1u);   // round-to-nearest-even
    return (unsigned short)(i >> 16);
}

// ---- Build MFMA B-fragments for W1 (f32 -> bf16), 16 K-steps ----
// frag layout: [step][lane][j] bf16; B-frag: lane holds B[k=(lane>>4)*8+j][n=lane&15]
__global__ void k_setup_frags(const float* __restrict__ W1,
                              unsigned short* __restrict__ bf1) {
    int idx = blockIdx.x * 256 + threadIdx.x;   // 32 blocks x 256 = 8192
    if (idx >= 16 * 64 * 8) return;
    int step = idx >> 9, lane = (idx >> 3) & 63, j = idx & 7;
    int n = lane & 15;
    int k = step * 32 + ((lane >> 4) * 8) + j;  // k < 512
    bf1[idx] = (n < HH) ? f2bf(W1[k * HH + n]) : (unsigned short)0;
}

__global__ void k_init(int* __restrict__ cnt, int* __restrict__ cur) {
    int i = blockIdx.x * 256 + threadIdx.x;
    if (i < NN) { cnt[i] = 0; cur[i] = 0; }
}

__global__ void k_count(const int* __restrict__ dst, int* __restrict__ cnt) {
    int e = blockIdx.x * 256 + threadIdx.x;
    if (e < EE) atomicAdd(&cnt[dst[e]], 1);
}

__global__ void k_scan_a(const int* __restrict__ cnt, int* __restrict__ row,
                         int* __restrict__ bsum) {
    __shared__ int s[256];
    int t = threadIdx.x, idx = blockIdx.x * 256 + t;
    int v = (idx < NN) ? cnt[idx] : 0;
    s[t] = v; __syncthreads();
    for (int off = 1; off < 256; off <<= 1) {
        int x = (t >= off) ? s[t - off] : 0;
        __syncthreads();
        if (t >= off) s[t] += x;
        __syncthreads();
    }
    if (idx < NN) row[idx] = s[t] - v;           // within-block exclusive
    if (t == 255) bsum[blockIdx.x] = s[255];     // block total
}

__global__ void k_scan_b(int* __restrict__ bsum) {
    __shared__ int s[256];
    int t = threadIdx.x;
    int v = (t < NBLK) ? bsum[t] : 0;
    s[t] = v; __syncthreads();
    for (int off = 1; off < 256; off <<= 1) {
        int x = (t >= off) ? s[t - off] : 0;
        __syncthreads();
        if (t >= off) s[t] += x;
        __syncthreads();
    }
    bsum[t] = s[t] - v;                          // exclusive block offsets
}

__global__ void k_finalize(const int* __restrict__ cnt, const int* __restrict__ bsum,
                           int* __restrict__ row, float* __restrict__ dinv) {
    int i = blockIdx.x * 256 + threadIdx.x;
    if (i < NN) {
        row[i] += bsum[i >> 8];
        dinv[i] = rsqrtf((float)cnt[i] + 1.0f);  // deg includes self-loop
    }
    if (i == 0) row[NN] = EE;
}

__global__ void k_fill(const int* __restrict__ src, const int* __restrict__ dst,
                       const int* __restrict__ row, int* __restrict__ cur,
                       const float* __restrict__ dinv, int2* __restrict__ elist) {
    int e = blockIdx.x * 256 + threadIdx.x;
    if (e >= EE) return;
    int s = src[e], d = dst[e];
    int pos = row[d] + atomicAdd(&cur[d], 1);
    float w = dinv[s] * dinv[d];
    elist[pos] = make_int2(s, __float_as_int(w));
}

// ---- t1 = x @ W1  via MFMA (f32 load -> bf16 cvt), one wave per 16 nodes ----
__global__ __launch_bounds__(256) void k_gemm1(const float4* __restrict__ x4,
                                               const uint4* __restrict__ bf1,
                                               float* __restrict__ t1) {
    int wave = threadIdx.x >> 6, lane = threadIdx.x & 63;
    int tile = blockIdx.x * 4 + wave;
    if (tile >= NTILE) return;
    int node0 = tile * 16;
    int m = lane & 15, q = lane >> 4;
    const float4* xrow = x4 + (size_t)(node0 + m) * (DD / 4) + q * 2;
    f32x4 acc = {0.f, 0.f, 0.f, 0.f};
#pragma unroll
    for (int step = 0; step < 16; ++step) {
        float4 u0 = xrow[step * 8];          // x[node0+m][step*32 + q*8 .. +3]
        float4 u1 = xrow[step * 8 + 1];      // .. +4..+7
        U16 a, b;
        a.h[0] = f2bf(u0.x); a.h[1] = f2bf(u0.y); a.h[2] = f2bf(u0.z); a.h[3] = f2bf(u0.w);
        a.h[4] = f2bf(u1.x); a.h[5] = f2bf(u1.y); a.h[6] = f2bf(u1.z); a.h[7] = f2bf(u1.w);
        b.u = bf1[step * 64 + lane];
        acc = __builtin_amdgcn_mfma_f32_16x16x32_bf16(a.v, b.v, acc, 0, 0, 0);
    }
    if (m < HH) {                              // C: col=lane&15, row=q*4+r
        int base = (node0 + q * 4) * HH + m;
        t1[base]          = acc[0];
        t1[base + HH]     = acc[1];
        t1[base + 2 * HH] = acc[2];
        t1[base + 3 * HH] = acc[3];
    }
}

// ---- agg1 = Ahat * t1 ; + b1 ; LayerNorm ; ReLU -> h2 ----
__global__ void k_agg1(const float4* __restrict__ t1v, const int* __restrict__ row,
                       const int2* __restrict__ elist, const float* __restrict__ dinv,
                       const float* __restrict__ b1,
                       const float* __restrict__ gma,
                       const float* __restrict__ bta,
                       float4* __restrict__ h2v) {
    int n = blockIdx.x * 256 + threadIdx.x;
    if (n >= NN) return;
    float dv = dinv[n], w0 = dv * dv;
    float4 p0 = t1v[2 * n], p1 = t1v[2 * n + 1];
    float a0 = p0.x * w0, a1 = p0.y * w0, a2 = p0.z * w0, a3 = p0.w * w0;
    float a4 = p1.x * w0, a5 = p1.y * w0, a6 = p1.z * w0, a7 = p1.w * w0;
    int e = row[n], end = row[n + 1];
    for (; e < end; ++e) {
        int2 r = elist[e];
        float w = __int_as_float(r.y);
        float4 q0 = t1v[2 * r.x], q1 = t1v[2 * r.x + 1];
        a0 += q0.x * w; a1 += q0.y * w; a2 += q0.z * w; a3 += q0.w * w;
        a4 += q1.x * w; a5 += q1.y * w; a6 += q1.z * w; a7 += q1.w * w;
    }
    a0 += b1[0]; a1 += b1[1]; a2 += b1[2]; a3 += b1[3];
    a4 += b1[4]; a5 += b1[5]; a6 += b1[6]; a7 += b1[7];
    float mu = (a0 + a1 + a2 + a3 + a4 + a5 + a6 + a7) * 0.125f;
    float d0 = a0 - mu, d1 = a1 - mu, d2 = a2 - mu, d3 = a3 - mu;
    float d4 = a4 - mu, d5 = a5 - mu, d6 = a6 - mu, d7 = a7 - mu;
    float var = (d0*d0 + d1*d1 + d2*d2 + d3*d3 + d4*d4 + d5*d5 + d6*d6 + d7*d7) * 0.125f;
    float rs = rsqrtf(var + 1e-5f);
    float r0 = fmaxf(d0 * rs * gma[0] + bta[0], 0.f);
    float r1 = fmaxf(d1 * rs * gma[1] + bta[1], 0.f);
    float r2 = fmaxf(d2 * rs * gma[2] + bta[2], 0.f);
    float r3 = fmaxf(d3 * rs * gma[3] + bta[3], 0.f);
    float r4 = fmaxf(d4 * rs * gma[4] + bta[4], 0.f);
    float r5 = fmaxf(d5 * rs * gma[5] + bta[5], 0.f);
    float r6 = fmaxf(d6 * rs * gma[6] + bta[6], 0.f);
    float r7 = fmaxf(d7 * rs * gma[7] + bta[7], 0.f);
    h2v[2 * n]     = make_float4(r0, r1, r2, r3);
    h2v[2 * n + 1] = make_float4(r4, r5, r6, r7);
}

// ---- agg2 = Ahat * h2 ----
__global__ void k_agg2(const float4* __restrict__ h2v, const int* __restrict__ row,
                       const int2* __restrict__ elist, const float* __restrict__ dinv,
                       float4* __restrict__ aggv) {
    int n = blockIdx.x * 256 + threadIdx.x;
    if (n >= NN) return;
    float dv = dinv[n], w0 = dv * dv;
    float4 p0 = h2v[2 * n], p1 = h2v[2 * n + 1];
    float a0 = p0.x * w0, a1 = p0.y * w0, a2 = p0.z * w0, a3 = p0.w * w0;
    float a4 = p1.x * w0, a5 = p1.y * w0, a6 = p1.z * w0, a7 = p1.w * w0;
    int e = row[n], end = row[n + 1];
    for (; e < end; ++e) {
        int2 r = elist[e];
        float w = __int_as_float(r.y);
        float4 q0 = h2v[2 * r.x], q1 = h2v[2 * r.x + 1];
        a0 += q0.x * w; a1 += q0.y * w; a2 += q0.z * w; a3 += q0.w * w;
        a4 += q1.x * w; a5 += q1.y * w; a6 += q1.z * w; a7 += q1.w * w;
    }
    aggv[2 * n]     = make_float4(a0, a1, a2, a3);
    aggv[2 * n + 1] = make_float4(a4, a5, a6, a7);
}

// ---- out = relu(agg2 @ W2 + b2) * sf : pure f32 VALU, W2 strip in registers ----
// Block 256 = 4 node-lanes (one per wave) x 64 column-threads (8 cols each).
// Each block covers 32 nodes; agg2 row loads are wave-uniform broadcasts.
__global__ __launch_bounds__(256) void k_gemm2(const float4* __restrict__ aggv,
                                               const float* __restrict__ W2,
                                               const float* __restrict__ b2,
                                               const float* __restrict__ sf,
                                               float* __restrict__ out) {
    int c = threadIdx.x & 63;         // column group: cols c*8 .. c*8+7
    int g = threadIdx.x >> 6;         // wave id = node sub-lane
    int d0 = c * 8;
    float w[8][8];
#pragma unroll
    for (int k = 0; k < 8; ++k) {
        float4 u0 = *(const float4*)(W2 + k * DD + d0);
        float4 u1 = *(const float4*)(W2 + k * DD + d0 + 4);
        w[k][0] = u0.x; w[k][1] = u0.y; w[k][2] = u0.z; w[k][3] = u0.w;
        w[k][4] = u1.x; w[k][5] = u1.y; w[k][6] = u1.z; w[k][7] = u1.w;
    }
    float bb[8];
    {
        float4 u0 = *(const float4*)(b2 + d0);
        float4 u1 = *(const float4*)(b2 + d0 + 4);
        bb[0] = u0.x; bb[1] = u0.y; bb[2] = u0.z; bb[3] = u0.w;
        bb[4] = u1.x; bb[5] = u1.y; bb[6] = u1.z; bb[7] = u1.w;
    }
#pragma unroll
    for (int i = 0; i < 8; ++i) {
        int n = blockIdx.x * 32 + i * 4 + g;   // wave-uniform
        if (n < NN) {
            float4 p0 = aggv[2 * n], p1 = aggv[2 * n + 1];   // broadcast
            float a[8] = {p0.x, p0.y, p0.z, p0.w, p1.x, p1.y, p1.z, p1.w};
            float s = sf[n];
            float acc[8];
#pragma unroll
            for (int j = 0; j < 8; ++j) acc[j] = bb[j];
#pragma unroll
            for (int k = 0; k < 8; ++k)
#pragma unroll
                for (int j = 0; j < 8; ++j) acc[j] += a[k] * w[k][j];
            float4 o0 = make_float4(fmaxf(acc[0], 0.f) * s, fmaxf(acc[1], 0.f) * s,
                                    fmaxf(acc[2], 0.f) * s, fmaxf(acc[3], 0.f) * s);
            float4 o1 = make_float4(fmaxf(acc[4], 0.f) * s, fmaxf(acc[5], 0.f) * s,
                                    fmaxf(acc[6], 0.f) * s, fmaxf(acc[7], 0.f) * s);
            float4* op = (float4*)(out + (size_t)n * DD + d0);
            op[0] = o0;
            op[1] = o1;
        }
    }
}

extern "C" void kernel_launch(void* const* d_in, const int* in_sizes, int n_in,
                              void* d_out, int out_size, void* d_ws, size_t ws_size,
                              hipStream_t stream) {
    (void)in_sizes; (void)n_in; (void)out_size; (void)ws_size;
    const float* x   = (const float*)d_in[0];
    const float* sf  = (const float*)d_in[1];
    const float* W1  = (const float*)d_in[2];
    const float* b1  = (const float*)d_in[3];
    const float* gma = (const float*)d_in[4];
    const float* bta = (const float*)d_in[5];
    const float* W2  = (const float*)d_in[6];
    const float* b2  = (const float*)d_in[7];
    const int* eidx  = (const int*)d_in[8];
    float* out = (float*)d_out;

    char* ws = (char*)d_ws;
    unsigned short* bf1 = (unsigned short*)(ws + 0);         // 16 KB
    int*   cnt   = (int*)(ws + 16384);                       // N ints
    int*   row   = (int*)(ws + 216384);                      // N+1 ints (+pad)
    int*   cur   = (int*)(ws + 416400);                      // N ints
    int*   bsum  = (int*)(ws + 616400);                      // 256 ints
    float* dinv  = (float*)(ws + 617424);                    // N f32
    float* t1    = (float*)(ws + 817424);                    // N*8 f32
    float* h2    = (float*)(ws + 2417424);                   // N*8 f32
    float* agg2  = (float*)(ws + 4017424);                   // N*8 f32
    int2*  elist = (int2*)(ws + 5617424);                    // E * 8B -> ends ~12.0 MB

    k_setup_frags<<<32, 256, 0, stream>>>(W1, bf1);
    k_init<<<NBLK, 256, 0, stream>>>(cnt, cur);
    k_count<<<EBLK, 256, 0, stream>>>(eidx + EE, cnt);
    k_scan_a<<<NBLK, 256, 0, stream>>>(cnt, row, bsum);
    k_scan_b<<<1, 256, 0, stream>>>(bsum);
    k_finalize<<<NBLK, 256, 0, stream>>>(cnt, bsum, row, dinv);
    k_fill<<<EBLK, 256, 0, stream>>>(eidx, eidx + EE, row, cur, dinv, elist);
    k_gemm1<<<(NTILE + 3) / 4, 256, 0, stream>>>((const float4*)x, (const uint4*)bf1, t1);
    k_agg1<<<NBLK, 256, 0, stream>>>((const float4*)t1, row, elist, dinv,
                                     b1, gma, bta, (float4*)h2);
    k_agg2<<<NBLK, 256, 0, stream>>>((const float4*)h2, row, elist, dinv,
                                     (float4*)agg2);
    k_gemm2<<<(NN + 31) / 32, 256, 0, stream>>>((const float4*)agg2, W2, b2, sf, out);
}

// Round 3
// 303.566 us; speedup vs baseline: 1.0928x; 1.0928x over previous
//
#include <hip/hip_runtime.h>

#define NN 50000
#define EE 800000
#define DD 512
#define HH 8
#define SLOTS 64          // max degree capacity; P(Poisson(16) >= 64) ~ 1e-20
#define NBLK 196          // ceil(NN/256)
#define NTILE (NN/16)     // 3125, exact
#define EBLK (EE/256)     // 3125, exact

typedef short bf16x8 __attribute__((ext_vector_type(8)));
typedef float f32x4 __attribute__((ext_vector_type(4)));

union U16 { uint4 u; bf16x8 v; unsigned short h[8]; };

__device__ __forceinline__ unsigned short f2bf(float f) {
    union { float f; unsigned int i; } c; c.f = f;
    unsigned int i = c.i;
    i += 0x7fffu + ((i >> 16) & 1u);   // round-to-nearest-even
    return (unsigned short)(i >> 16);
}

// ---- ONE atomic pass: slot fill + implicit degree count ----
// slots column-major: slots[pos*NN + d] = src, so gather reads coalesce.
__global__ void k_fill_ell(const int* __restrict__ src, const int* __restrict__ dst,
                           int* __restrict__ cur, int* __restrict__ slots) {
    int e = blockIdx.x * 256 + threadIdx.x;
    if (e >= EE) return;
    int s = src[e], d = dst[e];
    int pos = atomicAdd(&cur[d], 1);
    if (pos < SLOTS) slots[(size_t)pos * NN + d] = s;
}

// ---- t1 = x @ W1 via MFMA; W1 B-fragments built per-block in LDS ----
// B-frag (16x16x32 bf16): lane holds B[k=(lane>>4)*8+j][n=lane&15], j=0..7.
__global__ __launch_bounds__(256) void k_gemm1(const float4* __restrict__ x4,
                                               const float* __restrict__ W1,
                                               float* __restrict__ t1) {
    __shared__ unsigned short sbf[16 * 64 * 8];   // 16 KB: [step][lane][j]
    for (int i = threadIdx.x; i < 16 * 64 * 8; i += 256) {
        int lane = (i >> 3) & 63, j = i & 7;
        int n = lane & 15;
        int k = (i >> 9) * 32 + ((lane >> 4) * 8) + j;   // k < 512
        sbf[i] = (n < HH) ? f2bf(W1[k * HH + n]) : (unsigned short)0;
    }
    __syncthreads();
    int wave = threadIdx.x >> 6, lane = threadIdx.x & 63;
    int tile = blockIdx.x * 4 + wave;
    if (tile >= NTILE) return;
    int node0 = tile * 16;
    int m = lane & 15, q = lane >> 4;
    const float4* xrow = x4 + (size_t)(node0 + m) * (DD / 4) + q * 2;
    const uint4* bfrag = (const uint4*)sbf;
    f32x4 acc = {0.f, 0.f, 0.f, 0.f};
#pragma unroll
    for (int step = 0; step < 16; ++step) {
        float4 u0 = xrow[step * 8];
        float4 u1 = xrow[step * 8 + 1];
        U16 a, b;
        a.h[0] = f2bf(u0.x); a.h[1] = f2bf(u0.y); a.h[2] = f2bf(u0.z); a.h[3] = f2bf(u0.w);
        a.h[4] = f2bf(u1.x); a.h[5] = f2bf(u1.y); a.h[6] = f2bf(u1.z); a.h[7] = f2bf(u1.w);
        b.u = bfrag[step * 64 + lane];
        acc = __builtin_amdgcn_mfma_f32_16x16x32_bf16(a.v, b.v, acc, 0, 0, 0);
    }
    if (m < HH) {                              // C: col=lane&15, row=q*4+r
        int base = (node0 + q * 4) * HH + m;
        t1[base]          = acc[0];
        t1[base + HH]     = acc[1];
        t1[base + 2 * HH] = acc[2];
        t1[base + 3 * HH] = acc[3];
    }
}

// ---- agg1 = Ahat * t1 ; + b1 ; LayerNorm ; ReLU -> h2 ----
// a = dv * ( t1[n]*dv + sum_s t1[s]*dinv_s ) + b1 ; dinv recomputed from cur.
__global__ void k_agg1(const float4* __restrict__ t1v, const int* __restrict__ cur,
                       const int* __restrict__ slots,
                       const float* __restrict__ b1,
                       const float* __restrict__ gma,
                       const float* __restrict__ bta,
                       float4* __restrict__ h2v) {
    int n = blockIdx.x * 256 + threadIdx.x;
    if (n >= NN) return;
    int deg = cur[n]; if (deg > SLOTS) deg = SLOTS;
    float dv = rsqrtf((float)cur[n] + 1.0f);
    float4 p0 = t1v[2 * n], p1 = t1v[2 * n + 1];
    float a0 = p0.x * dv, a1 = p0.y * dv, a2 = p0.z * dv, a3 = p0.w * dv;
    float a4 = p1.x * dv, a5 = p1.y * dv, a6 = p1.z * dv, a7 = p1.w * dv;
    for (int i = 0; i < deg; ++i) {
        int s = slots[(size_t)i * NN + n];          // coalesced across lanes
        float ws = rsqrtf((float)cur[s] + 1.0f);
        float4 q0 = t1v[2 * s], q1 = t1v[2 * s + 1];
        a0 += q0.x * ws; a1 += q0.y * ws; a2 += q0.z * ws; a3 += q0.w * ws;
        a4 += q1.x * ws; a5 += q1.y * ws; a6 += q1.z * ws; a7 += q1.w * ws;
    }
    a0 = a0 * dv + b1[0]; a1 = a1 * dv + b1[1]; a2 = a2 * dv + b1[2]; a3 = a3 * dv + b1[3];
    a4 = a4 * dv + b1[4]; a5 = a5 * dv + b1[5]; a6 = a6 * dv + b1[6]; a7 = a7 * dv + b1[7];
    float mu = (a0 + a1 + a2 + a3 + a4 + a5 + a6 + a7) * 0.125f;
    float d0 = a0 - mu, d1 = a1 - mu, d2 = a2 - mu, d3 = a3 - mu;
    float d4 = a4 - mu, d5 = a5 - mu, d6 = a6 - mu, d7 = a7 - mu;
    float var = (d0*d0 + d1*d1 + d2*d2 + d3*d3 + d4*d4 + d5*d5 + d6*d6 + d7*d7) * 0.125f;
    float rs = rsqrtf(var + 1e-5f);
    float r0 = fmaxf(d0 * rs * gma[0] + bta[0], 0.f);
    float r1 = fmaxf(d1 * rs * gma[1] + bta[1], 0.f);
    float r2 = fmaxf(d2 * rs * gma[2] + bta[2], 0.f);
    float r3 = fmaxf(d3 * rs * gma[3] + bta[3], 0.f);
    float r4 = fmaxf(d4 * rs * gma[4] + bta[4], 0.f);
    float r5 = fmaxf(d5 * rs * gma[5] + bta[5], 0.f);
    float r6 = fmaxf(d6 * rs * gma[6] + bta[6], 0.f);
    float r7 = fmaxf(d7 * rs * gma[7] + bta[7], 0.f);
    h2v[2 * n]     = make_float4(r0, r1, r2, r3);
    h2v[2 * n + 1] = make_float4(r4, r5, r6, r7);
}

// ---- agg2 = Ahat * h2 (self-loop included) ----
__global__ void k_agg2(const float4* __restrict__ h2v, const int* __restrict__ cur,
                       const int* __restrict__ slots, float4* __restrict__ aggv) {
    int n = blockIdx.x * 256 + threadIdx.x;
    if (n >= NN) return;
    int deg = cur[n]; if (deg > SLOTS) deg = SLOTS;
    float dv = rsqrtf((float)cur[n] + 1.0f);
    float4 p0 = h2v[2 * n], p1 = h2v[2 * n + 1];
    float a0 = p0.x * dv, a1 = p0.y * dv, a2 = p0.z * dv, a3 = p0.w * dv;
    float a4 = p1.x * dv, a5 = p1.y * dv, a6 = p1.z * dv, a7 = p1.w * dv;
    for (int i = 0; i < deg; ++i) {
        int s = slots[(size_t)i * NN + n];
        float ws = rsqrtf((float)cur[s] + 1.0f);
        float4 q0 = h2v[2 * s], q1 = h2v[2 * s + 1];
        a0 += q0.x * ws; a1 += q0.y * ws; a2 += q0.z * ws; a3 += q0.w * ws;
        a4 += q1.x * ws; a5 += q1.y * ws; a6 += q1.z * ws; a7 += q1.w * ws;
    }
    aggv[2 * n]     = make_float4(a0 * dv, a1 * dv, a2 * dv, a3 * dv);
    aggv[2 * n + 1] = make_float4(a4 * dv, a5 * dv, a6 * dv, a7 * dv);
}

// ---- out = relu(agg2 @ W2 + b2) * sf : f32 VALU, W2 strip in registers ----
__global__ __launch_bounds__(256) void k_gemm2(const float4* __restrict__ aggv,
                                               const float* __restrict__ W2,
                                               const float* __restrict__ b2,
                                               const float* __restrict__ sf,
                                               float* __restrict__ out) {
    int c = threadIdx.x & 63;         // column group: cols c*8 .. c*8+7
    int g = threadIdx.x >> 6;         // wave id = node sub-lane
    int d0 = c * 8;
    float w[8][8];
#pragma unroll
    for (int k = 0; k < 8; ++k) {
        float4 u0 = *(const float4*)(W2 + k * DD + d0);
        float4 u1 = *(const float4*)(W2 + k * DD + d0 + 4);
        w[k][0] = u0.x; w[k][1] = u0.y; w[k][2] = u0.z; w[k][3] = u0.w;
        w[k][4] = u1.x; w[k][5] = u1.y; w[k][6] = u1.z; w[k][7] = u1.w;
    }
    float bb[8];
    {
        float4 u0 = *(const float4*)(b2 + d0);
        float4 u1 = *(const float4*)(b2 + d0 + 4);
        bb[0] = u0.x; bb[1] = u0.y; bb[2] = u0.z; bb[3] = u0.w;
        bb[4] = u1.x; bb[5] = u1.y; bb[6] = u1.z; bb[7] = u1.w;
    }
#pragma unroll
    for (int i = 0; i < 8; ++i) {
        int n = blockIdx.x * 32 + i * 4 + g;   // wave-uniform
        if (n < NN) {
            float4 p0 = aggv[2 * n], p1 = aggv[2 * n + 1];   // broadcast
            float a[8] = {p0.x, p0.y, p0.z, p0.w, p1.x, p1.y, p1.z, p1.w};
            float s = sf[n];
            float acc[8];
#pragma unroll
            for (int j = 0; j < 8; ++j) acc[j] = bb[j];
#pragma unroll
            for (int k = 0; k < 8; ++k)
#pragma unroll
                for (int j = 0; j < 8; ++j) acc[j] += a[k] * w[k][j];
            float4 o0 = make_float4(fmaxf(acc[0], 0.f) * s, fmaxf(acc[1], 0.f) * s,
                                    fmaxf(acc[2], 0.f) * s, fmaxf(acc[3], 0.f) * s);
            float4 o1 = make_float4(fmaxf(acc[4], 0.f) * s, fmaxf(acc[5], 0.f) * s,
                                    fmaxf(acc[6], 0.f) * s, fmaxf(acc[7], 0.f) * s);
            float4* op = (float4*)(out + (size_t)n * DD + d0);
            op[0] = o0;
            op[1] = o1;
        }
    }
}

extern "C" void kernel_launch(void* const* d_in, const int* in_sizes, int n_in,
                              void* d_out, int out_size, void* d_ws, size_t ws_size,
                              hipStream_t stream) {
    (void)in_sizes; (void)n_in; (void)out_size; (void)ws_size;
    const float* x   = (const float*)d_in[0];
    const float* sf  = (const float*)d_in[1];
    const float* W1  = (const float*)d_in[2];
    const float* b1  = (const float*)d_in[3];
    const float* gma = (const float*)d_in[4];
    const float* bta = (const float*)d_in[5];
    const float* W2  = (const float*)d_in[6];
    const float* b2  = (const float*)d_in[7];
    const int* eidx  = (const int*)d_in[8];
    float* out = (float*)d_out;

    char* ws = (char*)d_ws;
    int*   cur   = (int*)(ws + 0);                           // N ints (200 KB)
    int*   slots = (int*)(ws + (1 << 20));                   // SLOTS*N ints (12.8 MB)
    float* t1    = (float*)(ws + 15 * (1 << 20));            // N*8 f32 (1.6 MB)
    float* h2    = (float*)(ws + 17 * (1 << 20));            // N*8 f32
    float* agg2  = (float*)(ws + 19 * (1 << 20));            // N*8 f32

    hipMemsetAsync(cur, 0, NN * sizeof(int), stream);
    k_fill_ell<<<EBLK, 256, 0, stream>>>(eidx, eidx + EE, cur, slots);
    k_gemm1<<<(NTILE + 3) / 4, 256, 0, stream>>>((const float4*)x, W1, t1);
    k_agg1<<<NBLK, 256, 0, stream>>>((const float4*)t1, cur, slots,
                                     b1, gma, bta, (float4*)h2);
    k_agg2<<<NBLK, 256, 0, stream>>>((const float4*)h2, cur, slots,
                                     (float4*)agg2);
    k_gemm2<<<(NN + 31) / 32, 256, 0, stream>>>((const float4*)agg2, W2, b2, sf, out);
}

// Round 4
// 297.823 us; speedup vs baseline: 1.1139x; 1.0193x over previous
//
#include <hip/hip_runtime.h>

#define NN 50000
#define EE 800000
#define DD 512
#define HH 8
#define SLOTS 64          // max in-degree capacity; P(Poisson(16) >= 64) ~ 1e-20
#define GBLK 782          // ceil(NTILE/4) gemm1 blocks
#define EBLK 3125         // EE/256, exact
#define NTILE 3125        // NN/16, exact
#define AGBLK 1563        // ceil(NN*8/256) agg blocks / ceil(NN/32) gemm2 blocks

typedef short bf16x8 __attribute__((ext_vector_type(8)));
typedef float f32x4 __attribute__((ext_vector_type(4)));

union U16 { uint4 u; bf16x8 v; unsigned short h[8]; };

__device__ __forceinline__ unsigned short f2bf(float f) {
    union { float f; unsigned int i; } c; c.f = f;
    unsigned int i = c.i;
    i += 0x7fffu + ((i >> 16) & 1u);   // round-to-nearest-even
    return (unsigned short)(i >> 16);
}

// ================= K1: gemm1 (blocks 0..781)  ||  ELL fill (blocks 782..3906) ==
// gemm1: t1 = x @ W1 via MFMA, W1 B-frags staged in LDS.
// fill : one atomic pass; slots column-major (slots[pos*NN+d]=src) for coalesced
//        gather reads; cur[d] ends as in-degree.
__global__ __launch_bounds__(256) void k_fill_gemm1(const int* __restrict__ eidx,
                                                    const float4* __restrict__ x4,
                                                    const float* __restrict__ W1,
                                                    int* __restrict__ cur,
                                                    int* __restrict__ slots,
                                                    float* __restrict__ t1) {
    if (blockIdx.x >= GBLK) {
        int e = (blockIdx.x - GBLK) * 256 + threadIdx.x;
        if (e < EE) {
            int s = eidx[e], d = eidx[EE + e];
            int pos = atomicAdd(&cur[d], 1);
            if (pos < SLOTS) slots[(size_t)pos * NN + d] = s;
        }
        return;
    }
    __shared__ unsigned short sbf[16 * 64 * 8];   // 16 KB: [step][lane][j]
    for (int i = threadIdx.x; i < 16 * 64 * 8; i += 256) {
        int lane = (i >> 3) & 63, j = i & 7;
        int n = lane & 15;
        int k = (i >> 9) * 32 + ((lane >> 4) * 8) + j;
        sbf[i] = (n < HH) ? f2bf(W1[k * HH + n]) : (unsigned short)0;
    }
    __syncthreads();
    int wave = threadIdx.x >> 6, lane = threadIdx.x & 63;
    int tile = blockIdx.x * 4 + wave;
    if (tile >= NTILE) return;
    int node0 = tile * 16;
    int m = lane & 15, q = lane >> 4;
    const float4* xrow = x4 + (size_t)(node0 + m) * (DD / 4) + q * 2;
    const uint4* bfrag = (const uint4*)sbf;
    f32x4 acc = {0.f, 0.f, 0.f, 0.f};
#pragma unroll
    for (int step = 0; step < 16; ++step) {
        float4 u0 = xrow[step * 8];
        float4 u1 = xrow[step * 8 + 1];
        U16 a, b;
        a.h[0] = f2bf(u0.x); a.h[1] = f2bf(u0.y); a.h[2] = f2bf(u0.z); a.h[3] = f2bf(u0.w);
        a.h[4] = f2bf(u1.x); a.h[5] = f2bf(u1.y); a.h[6] = f2bf(u1.z); a.h[7] = f2bf(u1.w);
        b.u = bfrag[step * 64 + lane];
        acc = __builtin_amdgcn_mfma_f32_16x16x32_bf16(a.v, b.v, acc, 0, 0, 0);
    }
    if (m < HH) {                              // C: col=lane&15, row=q*4+r
        int base = (node0 + q * 4) * HH + m;
        t1[base]          = acc[0];
        t1[base + HH]     = acc[1];
        t1[base + 2 * HH] = acc[2];
        t1[base + 3 * HH] = acc[3];
    }
}

// ================= K2: agg1 + bias + LayerNorm + ReLU -> h2 ====================
// 8 threads per node (one per feature). Gathers are 32B-contiguous lane groups;
// LN via 3-step shfl_xor butterfly. Unroll x2 with branchless slot masking.
__global__ __launch_bounds__(256) void k_agg1(const float* __restrict__ t1,
                                              const int* __restrict__ cur,
                                              const int* __restrict__ slots,
                                              const float* __restrict__ b1,
                                              const float* __restrict__ gma,
                                              const float* __restrict__ bta,
                                              float* __restrict__ h2) {
    int gid = blockIdx.x * 256 + threadIdx.x;
    int n = gid >> 3, f = gid & 7;
    if (n >= NN) return;
    int degr = cur[n];
    int deg = degr > SLOTS ? SLOTS : degr;
    float dv = rsqrtf((float)degr + 1.0f);
    float acc = t1[(size_t)n * HH + f] * dv;
    int i = 0;
    while (__ballot(i < deg)) {
        int  s0r = slots[(size_t)i * NN + n];
        int  s1r = slots[(size_t)(i + 1) * NN + n];   // slots has SLOTS+1 rows
        bool v0 = i < deg, v1 = (i + 1) < deg;
        int  s0 = v0 ? s0r : 0, s1 = v1 ? s1r : 0;
        float w0 = v0 ? rsqrtf((float)cur[s0] + 1.0f) : 0.f;
        float w1 = v1 ? rsqrtf((float)cur[s1] + 1.0f) : 0.f;
        acc += t1[(size_t)s0 * HH + f] * w0;
        acc += t1[(size_t)s1 * HH + f] * w1;
        i += 2;
    }
    acc = acc * dv + b1[f];
    float s = acc;
    s += __shfl_xor(s, 1); s += __shfl_xor(s, 2); s += __shfl_xor(s, 4);
    float mu = s * 0.125f;
    float dx = acc - mu;
    float sq = dx * dx;
    sq += __shfl_xor(sq, 1); sq += __shfl_xor(sq, 2); sq += __shfl_xor(sq, 4);
    float var = sq * 0.125f;
    float rs = rsqrtf(var + 1e-5f);
    h2[(size_t)n * HH + f] = fmaxf(dx * rs * gma[f] + bta[f], 0.f);
}

// ================= K3: agg2 (phase A, to LDS) + gemm2 (phase B) ================
// Phase A: 8 threads/node x 32 nodes gather agg2 into LDS.
// Phase B: out = relu(agg2 @ W2 + b2) * sf, W2 strip in registers.
__global__ __launch_bounds__(256) void k_agg2_gemm2(const float* __restrict__ h2,
                                                    const int* __restrict__ cur,
                                                    const int* __restrict__ slots,
                                                    const float* __restrict__ W2,
                                                    const float* __restrict__ b2,
                                                    const float* __restrict__ sf,
                                                    float* __restrict__ out) {
    __shared__ float sA[32 * 8];
    int tid = threadIdx.x;
    int c = tid & 63, g = tid >> 6, d0 = c * 8;
    // start W2/b2 loads early — independent of phase A
    float w[8][8];
#pragma unroll
    for (int k = 0; k < 8; ++k) {
        float4 u0 = *(const float4*)(W2 + k * DD + d0);
        float4 u1 = *(const float4*)(W2 + k * DD + d0 + 4);
        w[k][0] = u0.x; w[k][1] = u0.y; w[k][2] = u0.z; w[k][3] = u0.w;
        w[k][4] = u1.x; w[k][5] = u1.y; w[k][6] = u1.z; w[k][7] = u1.w;
    }
    float bb[8];
    {
        float4 u0 = *(const float4*)(b2 + d0);
        float4 u1 = *(const float4*)(b2 + d0 + 4);
        bb[0] = u0.x; bb[1] = u0.y; bb[2] = u0.z; bb[3] = u0.w;
        bb[4] = u1.x; bb[5] = u1.y; bb[6] = u1.z; bb[7] = u1.w;
    }
    // ---- phase A ----
    int nl = tid >> 3, f = tid & 7;
    int n = blockIdx.x * 32 + nl;
    if (n < NN) {
        int degr = cur[n];
        int deg = degr > SLOTS ? SLOTS : degr;
        float dv = rsqrtf((float)degr + 1.0f);
        float acc = h2[(size_t)n * HH + f] * dv;
        int i = 0;
        while (__ballot(i < deg)) {
            int  s0r = slots[(size_t)i * NN + n];
            int  s1r = slots[(size_t)(i + 1) * NN + n];
            bool v0 = i < deg, v1 = (i + 1) < deg;
            int  s0 = v0 ? s0r : 0, s1 = v1 ? s1r : 0;
            float w0 = v0 ? rsqrtf((float)cur[s0] + 1.0f) : 0.f;
            float w1 = v1 ? rsqrtf((float)cur[s1] + 1.0f) : 0.f;
            acc += h2[(size_t)s0 * HH + f] * w0;
            acc += h2[(size_t)s1 * HH + f] * w1;
            i += 2;
        }
        sA[nl * 8 + f] = acc * dv;
    }
    __syncthreads();
    // ---- phase B ----
#pragma unroll
    for (int i = 0; i < 8; ++i) {
        int row = i * 4 + g;
        int n2 = blockIdx.x * 32 + row;
        if (n2 < NN) {
            float a[8];
#pragma unroll
            for (int j = 0; j < 8; ++j) a[j] = sA[row * 8 + j];   // LDS broadcast
            float s = sf[n2];
            float acc[8];
#pragma unroll
            for (int j = 0; j < 8; ++j) acc[j] = bb[j];
#pragma unroll
            for (int k = 0; k < 8; ++k)
#pragma unroll
                for (int j = 0; j < 8; ++j) acc[j] += a[k] * w[k][j];
            float4 o0 = make_float4(fmaxf(acc[0], 0.f) * s, fmaxf(acc[1], 0.f) * s,
                                    fmaxf(acc[2], 0.f) * s, fmaxf(acc[3], 0.f) * s);
            float4 o1 = make_float4(fmaxf(acc[4], 0.f) * s, fmaxf(acc[5], 0.f) * s,
                                    fmaxf(acc[6], 0.f) * s, fmaxf(acc[7], 0.f) * s);
            float4* op = (float4*)(out + (size_t)n2 * DD + d0);
            op[0] = o0;
            op[1] = o1;
        }
    }
}

extern "C" void kernel_launch(void* const* d_in, const int* in_sizes, int n_in,
                              void* d_out, int out_size, void* d_ws, size_t ws_size,
                              hipStream_t stream) {
    (void)in_sizes; (void)n_in; (void)out_size; (void)ws_size;
    const float* x   = (const float*)d_in[0];
    const float* sf  = (const float*)d_in[1];
    const float* W1  = (const float*)d_in[2];
    const float* b1  = (const float*)d_in[3];
    const float* gma = (const float*)d_in[4];
    const float* bta = (const float*)d_in[5];
    const float* W2  = (const float*)d_in[6];
    const float* b2  = (const float*)d_in[7];
    const int* eidx  = (const int*)d_in[8];
    float* out = (float*)d_out;

    char* ws = (char*)d_ws;
    int*   cur   = (int*)(ws + 0);                 // N ints (200 KB)
    int*   slots = (int*)(ws + (1 << 20));         // (SLOTS+1)*N ints (13 MB, +1 row for unroll overread)
    float* t1    = (float*)(ws + 16 * (1 << 20));  // N*8 f32 (1.6 MB)
    float* h2    = (float*)(ws + 18 * (1 << 20));  // N*8 f32

    hipMemsetAsync(cur, 0, NN * sizeof(int), stream);
    k_fill_gemm1<<<GBLK + EBLK, 256, 0, stream>>>(eidx, (const float4*)x, W1,
                                                  cur, slots, t1);
    k_agg1<<<AGBLK, 256, 0, stream>>>(t1, cur, slots, b1, gma, bta, h2);
    k_agg2_gemm2<<<AGBLK, 256, 0, stream>>>(h2, cur, slots, W2, b2, sf, out);
}

// Round 5
// 285.200 us; speedup vs baseline: 1.1632x; 1.0443x over previous
//
#include <hip/hip_runtime.h>

#define NN 50000
#define EE 800000
#define DD 512
#define HH 8
#define BA 160            // binning blocks (CHUNK = EE/BA exactly)
#define CHUNK 5000
#define NBIN 196          // coarse bins: dst >> 8
#define BCAP 4608         // per-bin edge capacity (mean 4096, sd 64; P(exceed) ~ 1e-13)
#define GBLK 782          // gemm1 tile blocks (4 tiles each)
#define NTILE 3125        // NN/16 exact
#define AGBLK 1563        // ceil(NN*8/256)

typedef short bf16x8 __attribute__((ext_vector_type(8)));
typedef float f32x4 __attribute__((ext_vector_type(4)));

union U16 { uint4 u; bf16x8 v; unsigned short h[8]; };

__device__ __forceinline__ unsigned short f2bf(float f) {
    union { float f; unsigned int i; } c; c.f = f;
    unsigned int i = c.i;
    i += 0x7fffu + ((i >> 16) & 1u);   // RNE
    return (unsigned short)(i >> 16);
}

// ===== K_A: per-block coarse histogram (LDS atomics only) =====================
__global__ __launch_bounds__(256) void k_hist(const int* __restrict__ dst,
                                              int* __restrict__ blockhist) {
    __shared__ int h[256];
    int t = threadIdx.x, blk = blockIdx.x;
    h[t] = 0; __syncthreads();
    int base = blk * CHUNK;
#pragma unroll
    for (int it = 0; it < 20; ++it) {
        int i = it * 256 + t;
        if (i < CHUNK) atomicAdd(&h[dst[base + i] >> 8], 1);
    }
    __syncthreads();
    blockhist[blk * 256 + t] = h[t];          // coalesced
}

// ===== K_B: scan -> global offsets per (blk,bin); binBase; row[NN] ============
__global__ __launch_bounds__(256) void k_scan(int* __restrict__ blockhist,
                                              int* __restrict__ binBase,
                                              int* __restrict__ row) {
    __shared__ int s[256];
    int t = threadIdx.x;
    int sum = 0;
    for (int b = 0; b < BA; ++b) sum += blockhist[b * 256 + t];   // coalesced
    s[t] = sum; __syncthreads();
    for (int off = 1; off < 256; off <<= 1) {
        int x = (t >= off) ? s[t - off] : 0;
        __syncthreads();
        if (t >= off) s[t] += x;
        __syncthreads();
    }
    int excl = s[t] - sum;
    binBase[t] = excl;
    if (t == 255) { binBase[256] = s[255]; row[NN] = s[255]; }
    int run = excl;
    for (int b = 0; b < BA; ++b) {
        int v = blockhist[b * 256 + t];
        blockhist[b * 256 + t] = run;
        run += v;
    }
}

// ===== K_C: scatter edges into coarse buckets (LDS cursors, no global atomics)
__global__ __launch_bounds__(256) void k_scatter(const int* __restrict__ eidx,
                                                 const int* __restrict__ blockhist,
                                                 int2* __restrict__ bucket) {
    __shared__ int cur[256];
    int t = threadIdx.x, blk = blockIdx.x;
    cur[t] = blockhist[blk * 256 + t]; __syncthreads();
    int base = blk * CHUNK;
#pragma unroll
    for (int it = 0; it < 20; ++it) {
        int i = it * 256 + t;
        if (i < CHUNK) {
            int s = eidx[base + i], d = eidx[EE + base + i];
            int pos = atomicAdd(&cur[d >> 8], 1);
            bucket[pos] = make_int2(s, d);
        }
    }
}

// ===== K_D: blocks 0..195 build CSR per bin; blocks 196.. run gemm1 ===========
// CSR: row[n], adj[row[n]..row[n+1]) = src list; dinvA[n] = rsqrt(indeg+1).
// gemm1: t1 = x @ W1 via mfma_f32_16x16x32_bf16, W1 B-frags staged in LDS.
__global__ __launch_bounds__(256) void k_build_gemm1(const int2* __restrict__ bucket,
                                                     const int* __restrict__ binBase,
                                                     const float4* __restrict__ x4,
                                                     const float* __restrict__ W1,
                                                     int* __restrict__ row,
                                                     int* __restrict__ adj,
                                                     float* __restrict__ dinvA,
                                                     float* __restrict__ t1) {
    __shared__ int smem[11264];                       // 45056 B, dual-use
    int t = threadIdx.x;
    if (blockIdx.x >= NBIN) {
        // ---------------- gemm1 path ----------------
        unsigned short* sbf = (unsigned short*)smem;  // 16 KB: [step][lane][j]
        for (int i = t; i < 16 * 64 * 8; i += 256) {
            int lane = (i >> 3) & 63, j = i & 7;
            int n = lane & 15;
            int k = (i >> 9) * 32 + ((lane >> 4) * 8) + j;
            sbf[i] = (n < HH) ? f2bf(W1[k * HH + n]) : (unsigned short)0;
        }
        __syncthreads();
        int wave = t >> 6, lane = t & 63;
        int tile = (blockIdx.x - NBIN) * 4 + wave;
        if (tile >= NTILE) return;
        int node0 = tile * 16;
        int m = lane & 15, q = lane >> 4;
        const float4* xrow = x4 + (size_t)(node0 + m) * (DD / 4) + q * 2;
        const uint4* bfrag = (const uint4*)sbf;
        f32x4 acc = {0.f, 0.f, 0.f, 0.f};
#pragma unroll
        for (int step = 0; step < 16; ++step) {
            float4 u0 = xrow[step * 8];
            float4 u1 = xrow[step * 8 + 1];
            U16 a, b;
            a.h[0] = f2bf(u0.x); a.h[1] = f2bf(u0.y); a.h[2] = f2bf(u0.z); a.h[3] = f2bf(u0.w);
            a.h[4] = f2bf(u1.x); a.h[5] = f2bf(u1.y); a.h[6] = f2bf(u1.z); a.h[7] = f2bf(u1.w);
            b.u = bfrag[step * 64 + lane];
            acc = __builtin_amdgcn_mfma_f32_16x16x32_bf16(a.v, b.v, acc, 0, 0, 0);
        }
        if (m < HH) {                                  // C: col=lane&15, row=q*4+r
            int base = (node0 + q * 4) * HH + m;
            t1[base]          = acc[0];
            t1[base + HH]     = acc[1];
            t1[base + 2 * HH] = acc[2];
            t1[base + 3 * HH] = acc[3];
        }
        return;
    }
    // ---------------- CSR-build path ----------------
    int bin = blockIdx.x;
    int n0 = bin << 8;
    int segStart = binBase[bin];
    int count = binBase[bin + 1] - segStart;
    if (count > BCAP) count = BCAP;                   // p ~ 0 guard
    int* lds_s   = smem;                              // BCAP ints
    int* lds_out = smem + BCAP;                       // BCAP ints
    int* cnt     = smem + 2 * BCAP;                   // 256
    int* off     = smem + 2 * BCAP + 256;             // 256
    int* cur2    = smem + 2 * BCAP + 512;             // 256
    unsigned char* lds_d = (unsigned char*)(smem + 2 * BCAP + 768);  // BCAP bytes
    cnt[t] = 0; __syncthreads();
    for (int i = t; i < count; i += 256) {
        int2 p = bucket[segStart + i];
        lds_s[i] = p.x;
        int dl = p.y - n0;
        lds_d[i] = (unsigned char)dl;
        atomicAdd(&cnt[dl], 1);
    }
    __syncthreads();
    off[t] = cnt[t]; __syncthreads();
    for (int o = 1; o < 256; o <<= 1) {
        int x = (t >= o) ? off[t - o] : 0;
        __syncthreads();
        if (t >= o) off[t] += x;
        __syncthreads();
    }
    int excl = off[t] - cnt[t];
    cur2[t] = excl;
    int n = n0 + t;
    if (n < NN) {
        row[n] = segStart + excl;
        dinvA[n] = rsqrtf((float)cnt[t] + 1.0f);
    }
    __syncthreads();
    for (int i = t; i < count; i += 256) {
        int pos = atomicAdd(&cur2[lds_d[i]], 1);
        lds_out[pos] = lds_s[i];
    }
    __syncthreads();
    for (int i = t; i < count; i += 256)
        adj[segStart + i] = lds_out[i];               // coalesced stream-out
}

// ===== K_E: agg1 + bias + LayerNorm + ReLU -> h2 (8 threads/node) =============
__global__ __launch_bounds__(256) void k_agg1(const float* __restrict__ t1,
                                              const int* __restrict__ row,
                                              const int* __restrict__ adj,
                                              const float* __restrict__ dinvA,
                                              const float* __restrict__ b1,
                                              const float* __restrict__ gma,
                                              const float* __restrict__ bta,
                                              float* __restrict__ h2) {
    int gid = blockIdx.x * 256 + threadIdx.x;
    int n = gid >> 3, f = gid & 7;
    if (n >= NN) return;
    int beg = row[n], end = row[n + 1];
    float dv = dinvA[n];
    float acc = t1[(size_t)n * HH + f] * dv;
    int i = beg;
    for (; i + 2 <= end; i += 2) {
        int s0 = adj[i], s1 = adj[i + 1];
        float w0 = dinvA[s0], w1 = dinvA[s1];
        acc += t1[(size_t)s0 * HH + f] * w0;
        acc += t1[(size_t)s1 * HH + f] * w1;
    }
    if (i < end) {
        int s0 = adj[i];
        acc += t1[(size_t)s0 * HH + f] * dinvA[s0];
    }
    acc = acc * dv + b1[f];
    float s = acc;
    s += __shfl_xor(s, 1); s += __shfl_xor(s, 2); s += __shfl_xor(s, 4);
    float mu = s * 0.125f;
    float dx = acc - mu;
    float sq = dx * dx;
    sq += __shfl_xor(sq, 1); sq += __shfl_xor(sq, 2); sq += __shfl_xor(sq, 4);
    float rs = rsqrtf(sq * 0.125f + 1e-5f);
    h2[(size_t)n * HH + f] = fmaxf(dx * rs * gma[f] + bta[f], 0.f);
}

// ===== K_F: agg2 (phase A -> LDS) + gemm2 (phase B) ===========================
__global__ __launch_bounds__(256) void k_agg2_gemm2(const float* __restrict__ h2,
                                                    const int* __restrict__ row,
                                                    const int* __restrict__ adj,
                                                    const float* __restrict__ dinvA,
                                                    const float* __restrict__ W2,
                                                    const float* __restrict__ b2,
                                                    const float* __restrict__ sf,
                                                    float* __restrict__ out) {
    __shared__ float sA[32 * 8];
    int tid = threadIdx.x;
    int c = tid & 63, g = tid >> 6, d0 = c * 8;
    float w[8][8];
#pragma unroll
    for (int k = 0; k < 8; ++k) {
        float4 u0 = *(const float4*)(W2 + k * DD + d0);
        float4 u1 = *(const float4*)(W2 + k * DD + d0 + 4);
        w[k][0] = u0.x; w[k][1] = u0.y; w[k][2] = u0.z; w[k][3] = u0.w;
        w[k][4] = u1.x; w[k][5] = u1.y; w[k][6] = u1.z; w[k][7] = u1.w;
    }
    float bb[8];
    {
        float4 u0 = *(const float4*)(b2 + d0);
        float4 u1 = *(const float4*)(b2 + d0 + 4);
        bb[0] = u0.x; bb[1] = u0.y; bb[2] = u0.z; bb[3] = u0.w;
        bb[4] = u1.x; bb[5] = u1.y; bb[6] = u1.z; bb[7] = u1.w;
    }
    // ---- phase A: agg2 for 32 nodes ----
    int nl = tid >> 3, f = tid & 7;
    int n = blockIdx.x * 32 + nl;
    if (n < NN) {
        int beg = row[n], end = row[n + 1];
        float dv = dinvA[n];
        float acc = h2[(size_t)n * HH + f] * dv;
        int i = beg;
        for (; i + 2 <= end; i += 2) {
            int s0 = adj[i], s1 = adj[i + 1];
            float w0 = dinvA[s0], w1 = dinvA[s1];
            acc += h2[(size_t)s0 * HH + f] * w0;
            acc += h2[(size_t)s1 * HH + f] * w1;
        }
        if (i < end) {
            int s0 = adj[i];
            acc += h2[(size_t)s0 * HH + f] * dinvA[s0];
        }
        sA[nl * 8 + f] = acc * dv;
    }
    __syncthreads();
    // ---- phase B: out = relu(agg2 @ W2 + b2) * sf ----
#pragma unroll
    for (int i = 0; i < 8; ++i) {
        int rrow = i * 4 + g;
        int n2 = blockIdx.x * 32 + rrow;
        if (n2 < NN) {
            float a[8];
#pragma unroll
            for (int j = 0; j < 8; ++j) a[j] = sA[rrow * 8 + j];
            float s = sf[n2];
            float acc[8];
#pragma unroll
            for (int j = 0; j < 8; ++j) acc[j] = bb[j];
#pragma unroll
            for (int k = 0; k < 8; ++k)
#pragma unroll
                for (int j = 0; j < 8; ++j) acc[j] += a[k] * w[k][j];
            float4 o0 = make_float4(fmaxf(acc[0], 0.f) * s, fmaxf(acc[1], 0.f) * s,
                                    fmaxf(acc[2], 0.f) * s, fmaxf(acc[3], 0.f) * s);
            float4 o1 = make_float4(fmaxf(acc[4], 0.f) * s, fmaxf(acc[5], 0.f) * s,
                                    fmaxf(acc[6], 0.f) * s, fmaxf(acc[7], 0.f) * s);
            float4* op = (float4*)(out + (size_t)n2 * DD + d0);
            op[0] = o0;
            op[1] = o1;
        }
    }
}

extern "C" void kernel_launch(void* const* d_in, const int* in_sizes, int n_in,
                              void* d_out, int out_size, void* d_ws, size_t ws_size,
                              hipStream_t stream) {
    (void)in_sizes; (void)n_in; (void)out_size; (void)ws_size;
    const float* x   = (const float*)d_in[0];
    const float* sf  = (const float*)d_in[1];
    const float* W1  = (const float*)d_in[2];
    const float* b1  = (const float*)d_in[3];
    const float* gma = (const float*)d_in[4];
    const float* bta = (const float*)d_in[5];
    const float* W2  = (const float*)d_in[6];
    const float* b2  = (const float*)d_in[7];
    const int* eidx  = (const int*)d_in[8];
    float* out = (float*)d_out;

    char* ws = (char*)d_ws;
    int*   blockhist = (int*)(ws + 0);                 // BA*256 ints = 160 KB
    int*   binBase   = (int*)(ws + 262144);            // 257 ints
    int*   row       = (int*)(ws + (1 << 20));         // NN+1 ints
    float* dinvA     = (float*)(ws + 2 * (1 << 20));   // NN f32
    float* t1        = (float*)(ws + 3 * (1 << 20));   // NN*8 f32 (1.6 MB)
    float* h2        = (float*)(ws + 5 * (1 << 20));   // NN*8 f32
    int*   adj       = (int*)(ws + 7 * (1 << 20));     // EE ints (3.2 MB)
    int2*  bucket    = (int2*)(ws + 11 * (1 << 20));   // EE int2 (6.4 MB)

    k_hist<<<BA, 256, 0, stream>>>(eidx + EE, blockhist);
    k_scan<<<1, 256, 0, stream>>>(blockhist, binBase, row);
    k_scatter<<<BA, 256, 0, stream>>>(eidx, blockhist, bucket);
    k_build_gemm1<<<NBIN + GBLK, 256, 0, stream>>>(bucket, binBase, (const float4*)x,
                                                   W1, row, adj, dinvA, t1);
    k_agg1<<<AGBLK, 256, 0, stream>>>(t1, row, adj, dinvA, b1, gma, bta, h2);
    k_agg2_gemm2<<<AGBLK, 256, 0, stream>>>(h2, row, adj, dinvA, W2, b2, sf, out);
}

// Round 6
// 282.496 us; speedup vs baseline: 1.1743x; 1.0096x over previous
//
#include <hip/hip_runtime.h>

#define NN 50000
#define EE 800000
#define DD 512
#define HH 8
#define BA 160            // binning blocks (CHUNK = EE/BA exactly)
#define CHUNK 5000
#define NBIN 196          // coarse bins: dst >> 8
#define BCAP 4608         // per-bin edge capacity (mean 4096, sd 64; P(exceed) ~ 1e-13)
#define GBLK 782          // gemm1 tile blocks (4 tiles each)
#define NTILE 3125        // NN/16 exact
#define AGBLK 1563        // ceil(NN*8/256)

typedef short bf16x8 __attribute__((ext_vector_type(8)));
typedef float f32x4 __attribute__((ext_vector_type(4)));

union U16 { uint4 u; bf16x8 v; unsigned short h[8]; };

__device__ __forceinline__ unsigned short f2bf(float f) {
    union { float f; unsigned int i; } c; c.f = f;
    unsigned int i = c.i;
    i += 0x7fffu + ((i >> 16) & 1u);   // RNE
    return (unsigned short)(i >> 16);
}

// ===== K1: gemm1 (blocks 0..GBLK-1, 16KB LDS, pipelined loads) || hist ========
__global__ __launch_bounds__(256) void k_gemm1_hist(const float4* __restrict__ x4,
                                                    const float* __restrict__ W1,
                                                    const int* __restrict__ dst,
                                                    float* __restrict__ t1,
                                                    int* __restrict__ blockhist) {
    __shared__ int smem[4096];                        // 16 KB dual-use
    int t = threadIdx.x;
    if (blockIdx.x >= GBLK) {
        // ---------------- histogram path ----------------
        int blk = blockIdx.x - GBLK;
        int* h = smem;
        h[t] = 0; __syncthreads();
        int base = blk * CHUNK;
#pragma unroll
        for (int it = 0; it < 20; ++it) {
            int i = it * 256 + t;
            if (i < CHUNK) atomicAdd(&h[dst[base + i] >> 8], 1);
        }
        __syncthreads();
        blockhist[blk * 256 + t] = h[t];
        return;
    }
    // ---------------- gemm1 path ----------------
    unsigned short* sbf = (unsigned short*)smem;      // 16 KB: [step][lane][j]
    for (int i = t; i < 16 * 64 * 8; i += 256) {
        int lane = (i >> 3) & 63, j = i & 7;
        int n = lane & 15;
        int k = (i >> 9) * 32 + ((lane >> 4) * 8) + j;
        sbf[i] = (n < HH) ? f2bf(W1[k * HH + n]) : (unsigned short)0;
    }
    __syncthreads();
    int wave = t >> 6, lane = t & 63;
    int tile = blockIdx.x * 4 + wave;
    if (tile >= NTILE) return;
    int node0 = tile * 16;
    int m = lane & 15, q = lane >> 4;
    const float4* xrow = x4 + (size_t)(node0 + m) * (DD / 4) + q * 2;
    const uint4* bfrag = (const uint4*)sbf;
    f32x4 acc = {0.f, 0.f, 0.f, 0.f};

    float4 bufA[8], bufB[8];
#define LOADG(buf, g)                                                      \
    _Pragma("unroll")                                                      \
    for (int s = 0; s < 4; ++s) {                                          \
        buf[2 * s]     = xrow[((g) * 4 + s) * 8];                          \
        buf[2 * s + 1] = xrow[((g) * 4 + s) * 8 + 1];                      \
    }
#define MFMAG(buf, g)                                                      \
    _Pragma("unroll")                                                      \
    for (int s = 0; s < 4; ++s) {                                          \
        U16 a, b;                                                          \
        float4 u0 = buf[2 * s], u1 = buf[2 * s + 1];                       \
        a.h[0] = f2bf(u0.x); a.h[1] = f2bf(u0.y);                          \
        a.h[2] = f2bf(u0.z); a.h[3] = f2bf(u0.w);                          \
        a.h[4] = f2bf(u1.x); a.h[5] = f2bf(u1.y);                          \
        a.h[6] = f2bf(u1.z); a.h[7] = f2bf(u1.w);                          \
        b.u = bfrag[((g) * 4 + s) * 64 + lane];                            \
        acc = __builtin_amdgcn_mfma_f32_16x16x32_bf16(a.v, b.v, acc, 0, 0, 0); \
    }
    LOADG(bufA, 0)
    LOADG(bufB, 1)
    MFMAG(bufA, 0)
    LOADG(bufA, 2)
    MFMAG(bufB, 1)
    LOADG(bufB, 3)
    MFMAG(bufA, 2)
    MFMAG(bufB, 3)
#undef LOADG
#undef MFMAG
    if (m < HH) {                                      // C: col=lane&15, row=q*4+r
        int base = (node0 + q * 4) * HH + m;
        t1[base]          = acc[0];
        t1[base + HH]     = acc[1];
        t1[base + 2 * HH] = acc[2];
        t1[base + 3 * HH] = acc[3];
    }
}

// ===== K2: scan -> global offsets per (blk,bin); binBase ======================
__global__ __launch_bounds__(256) void k_scan(int* __restrict__ blockhist,
                                              int* __restrict__ binBase,
                                              int* __restrict__ row) {
    __shared__ int s[256];
    int t = threadIdx.x;
    int sum = 0;
    for (int b = 0; b < BA; ++b) sum += blockhist[b * 256 + t];   // coalesced
    s[t] = sum; __syncthreads();
    for (int off = 1; off < 256; off <<= 1) {
        int x = (t >= off) ? s[t - off] : 0;
        __syncthreads();
        if (t >= off) s[t] += x;
        __syncthreads();
    }
    int excl = s[t] - sum;
    binBase[t] = excl;
    if (t == 255) { binBase[256] = s[255]; row[NN] = s[255]; }
    int run = excl;
    for (int b = 0; b < BA; ++b) {
        int v = blockhist[b * 256 + t];
        blockhist[b * 256 + t] = run;
        run += v;
    }
}

// ===== K3: scatter edges into coarse buckets; packed (src<<8)|dst_local =======
__global__ __launch_bounds__(256) void k_scatter(const int* __restrict__ eidx,
                                                 const int* __restrict__ blockhist,
                                                 int* __restrict__ bucket) {
    __shared__ int cur[256];
    int t = threadIdx.x, blk = blockIdx.x;
    cur[t] = blockhist[blk * 256 + t]; __syncthreads();
    int base = blk * CHUNK;
#pragma unroll
    for (int it = 0; it < 20; ++it) {
        int i = it * 256 + t;
        if (i < CHUNK) {
            int s = eidx[base + i], d = eidx[EE + base + i];
            int pos = atomicAdd(&cur[d >> 8], 1);
            bucket[pos] = (s << 8) | (d & 255);
        }
    }
}

// ===== K4: build CSR per bin (LDS counting sort) ==============================
__global__ __launch_bounds__(256) void k_build(const int* __restrict__ bucket,
                                               const int* __restrict__ binBase,
                                               int* __restrict__ row,
                                               int* __restrict__ adj,
                                               float* __restrict__ dinvA) {
    __shared__ int smem[2 * BCAP + 768];              // ~39.9 KB
    int t = threadIdx.x;
    int bin = blockIdx.x;
    int n0 = bin << 8;
    int segStart = binBase[bin];
    int count = binBase[bin + 1] - segStart;
    if (count > BCAP) count = BCAP;                   // p ~ 0 guard
    int* lds_in  = smem;                              // packed entries
    int* lds_out = smem + BCAP;
    int* cnt     = smem + 2 * BCAP;
    int* off     = smem + 2 * BCAP + 256;
    int* cur2    = smem + 2 * BCAP + 512;
    cnt[t] = 0; __syncthreads();
    for (int i = t; i < count; i += 256) {
        int p = bucket[segStart + i];
        lds_in[i] = p;
        atomicAdd(&cnt[p & 255], 1);
    }
    __syncthreads();
    off[t] = cnt[t]; __syncthreads();
    for (int o = 1; o < 256; o <<= 1) {
        int x = (t >= o) ? off[t - o] : 0;
        __syncthreads();
        if (t >= o) off[t] += x;
        __syncthreads();
    }
    int excl = off[t] - cnt[t];
    cur2[t] = excl;
    int n = n0 + t;
    if (n < NN) {
        row[n] = segStart + excl;
        dinvA[n] = rsqrtf((float)cnt[t] + 1.0f);
    }
    __syncthreads();
    for (int i = t; i < count; i += 256) {
        int p = lds_in[i];
        int pos = atomicAdd(&cur2[p & 255], 1);
        lds_out[pos] = p >> 8;                        // src
    }
    __syncthreads();
    for (int i = t; i < count; i += 256)
        adj[segStart + i] = lds_out[i];               // coalesced stream-out
}

// ===== K5: agg1 + bias + LayerNorm + ReLU -> h2 (8 threads/node) ==============
__global__ __launch_bounds__(256) void k_agg1(const float* __restrict__ t1,
                                              const int* __restrict__ row,
                                              const int* __restrict__ adj,
                                              const float* __restrict__ dinvA,
                                              const float* __restrict__ b1,
                                              const float* __restrict__ gma,
                                              const float* __restrict__ bta,
                                              float* __restrict__ h2) {
    int gid = blockIdx.x * 256 + threadIdx.x;
    int n = gid >> 3, f = gid & 7;
    if (n >= NN) return;
    int beg = row[n], end = row[n + 1];
    float dv = dinvA[n];
    float acc = t1[(size_t)n * HH + f] * dv;
    int i = beg;
    for (; i + 2 <= end; i += 2) {
        int s0 = adj[i], s1 = adj[i + 1];
        float w0 = dinvA[s0], w1 = dinvA[s1];
        acc += t1[(size_t)s0 * HH + f] * w0;
        acc += t1[(size_t)s1 * HH + f] * w1;
    }
    if (i < end) {
        int s0 = adj[i];
        acc += t1[(size_t)s0 * HH + f] * dinvA[s0];
    }
    acc = acc * dv + b1[f];
    float s = acc;
    s += __shfl_xor(s, 1); s += __shfl_xor(s, 2); s += __shfl_xor(s, 4);
    float mu = s * 0.125f;
    float dx = acc - mu;
    float sq = dx * dx;
    sq += __shfl_xor(sq, 1); sq += __shfl_xor(sq, 2); sq += __shfl_xor(sq, 4);
    float rs = rsqrtf(sq * 0.125f + 1e-5f);
    h2[(size_t)n * HH + f] = fmaxf(dx * rs * gma[f] + bta[f], 0.f);
}

// ===== K6: agg2 (phase A -> LDS) + gemm2 (phase B) ============================
__global__ __launch_bounds__(256) void k_agg2_gemm2(const float* __restrict__ h2,
                                                    const int* __restrict__ row,
                                                    const int* __restrict__ adj,
                                                    const float* __restrict__ dinvA,
                                                    const float* __restrict__ W2,
                                                    const float* __restrict__ b2,
                                                    const float* __restrict__ sf,
                                                    float* __restrict__ out) {
    __shared__ float sA[32 * 8];
    int tid = threadIdx.x;
    int c = tid & 63, g = tid >> 6, d0 = c * 8;
    float w[8][8];
#pragma unroll
    for (int k = 0; k < 8; ++k) {
        float4 u0 = *(const float4*)(W2 + k * DD + d0);
        float4 u1 = *(const float4*)(W2 + k * DD + d0 + 4);
        w[k][0] = u0.x; w[k][1] = u0.y; w[k][2] = u0.z; w[k][3] = u0.w;
        w[k][4] = u1.x; w[k][5] = u1.y; w[k][6] = u1.z; w[k][7] = u1.w;
    }
    float bb[8];
    {
        float4 u0 = *(const float4*)(b2 + d0);
        float4 u1 = *(const float4*)(b2 + d0 + 4);
        bb[0] = u0.x; bb[1] = u0.y; bb[2] = u0.z; bb[3] = u0.w;
        bb[4] = u1.x; bb[5] = u1.y; bb[6] = u1.z; bb[7] = u1.w;
    }
    // ---- phase A: agg2 for 32 nodes ----
    int nl = tid >> 3, f = tid & 7;
    int n = blockIdx.x * 32 + nl;
    if (n < NN) {
        int beg = row[n], end = row[n + 1];
        float dv = dinvA[n];
        float acc = h2[(size_t)n * HH + f] * dv;
        int i = beg;
        for (; i + 2 <= end; i += 2) {
            int s0 = adj[i], s1 = adj[i + 1];
            float w0 = dinvA[s0], w1 = dinvA[s1];
            acc += h2[(size_t)s0 * HH + f] * w0;
            acc += h2[(size_t)s1 * HH + f] * w1;
        }
        if (i < end) {
            int s0 = adj[i];
            acc += h2[(size_t)s0 * HH + f] * dinvA[s0];
        }
        sA[nl * 8 + f] = acc * dv;
    }
    __syncthreads();
    // ---- phase B: out = relu(agg2 @ W2 + b2) * sf ----
#pragma unroll
    for (int i = 0; i < 8; ++i) {
        int rrow = i * 4 + g;
        int n2 = blockIdx.x * 32 + rrow;
        if (n2 < NN) {
            float a[8];
#pragma unroll
            for (int j = 0; j < 8; ++j) a[j] = sA[rrow * 8 + j];
            float s = sf[n2];
            float acc[8];
#pragma unroll
            for (int j = 0; j < 8; ++j) acc[j] = bb[j];
#pragma unroll
            for (int k = 0; k < 8; ++k)
#pragma unroll
                for (int j = 0; j < 8; ++j) acc[j] += a[k] * w[k][j];
            float4 o0 = make_float4(fmaxf(acc[0], 0.f) * s, fmaxf(acc[1], 0.f) * s,
                                    fmaxf(acc[2], 0.f) * s, fmaxf(acc[3], 0.f) * s);
            float4 o1 = make_float4(fmaxf(acc[4], 0.f) * s, fmaxf(acc[5], 0.f) * s,
                                    fmaxf(acc[6], 0.f) * s, fmaxf(acc[7], 0.f) * s);
            float4* op = (float4*)(out + (size_t)n2 * DD + d0);
            op[0] = o0;
            op[1] = o1;
        }
    }
}

extern "C" void kernel_launch(void* const* d_in, const int* in_sizes, int n_in,
                              void* d_out, int out_size, void* d_ws, size_t ws_size,
                              hipStream_t stream) {
    (void)in_sizes; (void)n_in; (void)out_size; (void)ws_size;
    const float* x   = (const float*)d_in[0];
    const float* sf  = (const float*)d_in[1];
    const float* W1  = (const float*)d_in[2];
    const float* b1  = (const float*)d_in[3];
    const float* gma = (const float*)d_in[4];
    const float* bta = (const float*)d_in[5];
    const float* W2  = (const float*)d_in[6];
    const float* b2  = (const float*)d_in[7];
    const int* eidx  = (const int*)d_in[8];
    float* out = (float*)d_out;

    char* ws = (char*)d_ws;
    int*   blockhist = (int*)(ws + 0);                 // BA*256 ints = 160 KB
    int*   binBase   = (int*)(ws + 262144);            // 257 ints
    int*   row       = (int*)(ws + (1 << 20));         // NN+1 ints
    float* dinvA     = (float*)(ws + 2 * (1 << 20));   // NN f32
    float* t1        = (float*)(ws + 3 * (1 << 20));   // NN*8 f32 (1.6 MB)
    float* h2        = (float*)(ws + 5 * (1 << 20));   // NN*8 f32
    int*   adj       = (int*)(ws + 7 * (1 << 20));     // EE ints (3.2 MB)
    int*   bucket    = (int*)(ws + 11 * (1 << 20));    // EE ints (3.2 MB)

    k_gemm1_hist<<<GBLK + BA, 256, 0, stream>>>((const float4*)x, W1, eidx + EE,
                                                t1, blockhist);
    k_scan<<<1, 256, 0, stream>>>(blockhist, binBase, row);
    k_scatter<<<BA, 256, 0, stream>>>(eidx, blockhist, bucket);
    k_build<<<NBIN, 256, 0, stream>>>(bucket, binBase, row, adj, dinvA);
    k_agg1<<<AGBLK, 256, 0, stream>>>(t1, row, adj, dinvA, b1, gma, bta, h2);
    k_agg2_gemm2<<<AGBLK, 256, 0, stream>>>(h2, row, adj, dinvA, W2, b2, sf, out);
}